// Round 12
// baseline (10055.923 us; speedup 1.0000x reference)
//
#include <hip/hip_runtime.h>
#include <math.h>

#define B_ 8
#define N_ 16384
#define M_ 4096
#define D_ 512
#define TPB 1024
#define PPT 16          // N_ / TPB points per thread

#define FEAT_SZ (B_ * M_ * D_)          // 16777216
#define COFF FEAT_SZ                    // coords_out
#define TOFF (FEAT_SZ + 2 * B_ * M_)    // times_out
#define POFF (TOFF + B_ * M_)           // pol_out

#define R16(F) F(0) F(1) F(2) F(3) F(4) F(5) F(6) F(7) \
               F(8) F(9) F(10) F(11) F(12) F(13) F(14) F(15)

__device__ __forceinline__ unsigned spread4(unsigned v) {
    return (v & 1u) | ((v & 2u) << 2) | ((v & 4u) << 4) | ((v & 8u) << 6);
}
__device__ __forceinline__ unsigned mcode(float x, float y, float tt) {
    unsigned mx = min((unsigned)(int)(x * 16.0f), 15u);
    unsigned my = min((unsigned)(int)(y * 16.0f), 15u);
    unsigned mt = min((unsigned)(int)(tt * 16.0f), 15u);
    return spread4(mx) | (spread4(my) << 1) | (spread4(mt) << 2);   // 12-bit Morton
}

// ---------------------------------------------------------------------------
// Kernel 0: Morton counting-sort (per batch) — unchanged from r11 (verified).
// ---------------------------------------------------------------------------
__global__ __launch_bounds__(TPB) void msort_kernel(
    const float* __restrict__ coords, const float* __restrict__ times,
    float* __restrict__ sortx, float* __restrict__ sorty,
    float* __restrict__ sortt, unsigned* __restrict__ sortid)
{
    const int b = blockIdx.x, t = threadIdx.x;
    const float* cb = coords + (size_t)b * N_ * 2;
    const float* tb = times + (size_t)b * N_;
    const size_t bo = (size_t)b * N_;

    __shared__ unsigned cnt[4096];
    __shared__ unsigned wsum[TPB];

    for (int i = t; i < 4096; i += TPB) cnt[i] = 0;
    __syncthreads();

    for (int j = 0; j < PPT; ++j) {                 // count
        const int gi = j * TPB + t;
        const float2 c2 = *(const float2*)(cb + 2 * (size_t)gi);
        atomicAdd(&cnt[mcode(c2.x, c2.y, tb[gi])], 1u);
    }
    __syncthreads();

    {   // exclusive prefix sum over 4096
        const unsigned c0 = cnt[4 * t], c1 = cnt[4 * t + 1],
                       c2 = cnt[4 * t + 2], c3 = cnt[4 * t + 3];
        wsum[t] = c0 + c1 + c2 + c3;
        __syncthreads();
        if (t == 0) {
            unsigned run = 0;
            for (int i = 0; i < TPB; ++i) { unsigned v = wsum[i]; wsum[i] = run; run += v; }
        }
        __syncthreads();
        const unsigned base = wsum[t];
        cnt[4 * t] = base;
        cnt[4 * t + 1] = base + c0;
        cnt[4 * t + 2] = base + c0 + c1;
        cnt[4 * t + 3] = base + c0 + c1 + c2;
    }
    __syncthreads();

    for (int j = 0; j < PPT; ++j) {                 // scatter
        const int gi = j * TPB + t;
        const float2 c2 = *(const float2*)(cb + 2 * (size_t)gi);
        const float tt = tb[gi];
        const unsigned pos = atomicAdd(&cnt[mcode(c2.x, c2.y, tt)], 1u);
        sortx[bo + pos] = c2.x;
        sorty[bo + pos] = c2.y;
        sortt[bo + pos] = tt;
        sortid[bo + pos] = (unsigned)gi;
    }
}

// ---------------------------------------------------------------------------
// Kernel 1: FPS with exact bbox pruning + cached keys + SINGLE barrier/iter.
//
// Bit-exact chain (verified r2-r11): d2 = fma(dz,dz, fma(dx,dx, dy*dy));
// s = sqrt_rn(fadd_rn(d2,1e-8)); min in d2 domain; s-domain argmax,
// first-ORIG-index tie-break, sqrt-collapse ulp-window fixup.
//
// r11 lesson: pruning cut VALU 2x but wall time rose — the 2-barrier skeleton
// (DPP+bar+scan+winner-detour+atomics+bar+reads, ~3.6k cy) is the floor.
// This round: thread caches its packed candidate key
//   key = (s_bits<<32) | (N-1-origid)<<14 | sortedpos   (+ t payload)
// (valid while the thread skips — its m_i are unchanged). Update path (rare,
// Morton-clustered) recomputes key incl. SEL/fixup. Per iteration:
//   bbox test -> [rare update] -> wave butterfly max (skipped if no lane
//   updated; cached wave key) -> lane0 writes 16B (key,t) -> ONE barrier ->
//   all threads scan 16 structs (broadcast b128) -> unpack: lt from payload,
//   lx/ly from cxy[pos]. No atomics, no second barrier, no global loads.
// ---------------------------------------------------------------------------
__global__ __launch_bounds__(TPB)
__attribute__((amdgpu_waves_per_eu(4, 4)))
void fps_kernel(
    const float* __restrict__ coords, const float* __restrict__ times,
    const float* __restrict__ sortx, const float* __restrict__ sorty,
    const float* __restrict__ sortt, const unsigned* __restrict__ sortid,
    int* __restrict__ idx_out)
{
    const int b = blockIdx.x;
    const int t = threadIdx.x;
    const float* cb = coords + (size_t)b * N_ * 2;
    const float* tb = times + (size_t)b * N_;
    const size_t bo = (size_t)b * N_;

    __shared__ float2 cxy[N_];          // sorted pos p at [(p&15)*TPB + (p>>4)]
    __shared__ __align__(16) ulonglong2 red[2][16];   // (key, t_bits) per wave

#define DECLV(i) float pt##i, m##i;
    R16(DECLV)
#undef DECLV
    unsigned id2_0, id2_1, id2_2, id2_3, id2_4, id2_5, id2_6, id2_7;

    float bx0 = 1e30f, bx1 = -1e30f, by0 = 1e30f, by1 = -1e30f,
          bt0 = 1e30f, bt1 = -1e30f;

#define LOADV(i) { const int p = t * PPT + (i);                               \
        const float x = sortx[bo + p], y = sorty[bo + p], tt = sortt[bo + p]; \
        float2 v2; v2.x = x; v2.y = y;                                        \
        cxy[(i) * TPB + t] = v2;                                              \
        pt##i = tt; m##i = INFINITY;                                          \
        bx0 = fminf(bx0, x); bx1 = fmaxf(bx1, x);                             \
        by0 = fminf(by0, y); by1 = fmaxf(by1, y);                             \
        bt0 = fminf(bt0, tt); bt1 = fmaxf(bt1, tt); }
    R16(LOADV)
#undef LOADV

#define LOADID(r) id2_##r = (sortid[bo + t * PPT + 2 * (r)] & 0xffffu) |      \
                            (sortid[bo + t * PPT + 2 * (r) + 1] << 16);
    LOADID(0) LOADID(1) LOADID(2) LOADID(3)
    LOADID(4) LOADID(5) LOADID(6) LOADID(7)
#undef LOADID

#define PINV(i) asm("" : "+v"(pt##i));
    R16(PINV)
#undef PINV
    asm("" : "+v"(id2_0), "+v"(id2_1), "+v"(id2_2), "+v"(id2_3));
    asm("" : "+v"(id2_4), "+v"(id2_5), "+v"(id2_6), "+v"(id2_7));

    if (t == 0) idx_out[b * M_] = 0;                // deterministic seed
    float lx = cb[0], ly = cb[1], lt = tb[0];
    float TM = INFINITY;
    unsigned long long skey = 0ull;                 // cached packed candidate
    float sbt = 0.0f;                               // cached t payload
    unsigned long long wkey = 0ull;                 // cached wave-reduced key
    float wbt = 0.0f;
    __syncthreads();

    const int wave = t >> 6;
    const int lane = t & 63;

    for (int k = 1; k < M_; ++k) {
        const int par = k & 1;

        // ---- exact bbox skip test
        const float ddx = fmaxf(fmaxf(bx0 - lx, lx - bx1), 0.0f);
        const float ddy = fmaxf(fmaxf(by0 - ly, ly - by1), 0.0f);
        const float ddt = fmaxf(fmaxf(bt0 - lt, lt - bt1), 0.0f);
        const float lb2 = __fmaf_rn(ddt, ddt,
                          __fmaf_rn(ddx, ddx, __fmul_rn(ddy, ddy)));
        const bool upd = !(lb2 * 0.999996f >= TM);

        if (upd) {
            // ---- rare update path: refresh mins, TM, and the cached key
#define UPDV(i) { const float2 c2 = cxy[(i) * TPB + t];                       \
            const float dx = c2.x - lx;                                       \
            const float dy = c2.y - ly;                                       \
            const float dz = pt##i - lt;                                      \
            const float d2 = __fmaf_rn(dz, dz, __fmaf_rn(dx, dx,              \
                                                     __fmul_rn(dy, dy)));     \
            m##i = fminf(m##i, d2); }
            R16(UPDV)
#undef UPDV
            const float a0 = fmaxf(fmaxf(m0, m1), m2);
            const float a1 = fmaxf(fmaxf(m3, m4), m5);
            const float a2 = fmaxf(fmaxf(m6, m7), m8);
            const float a3 = fmaxf(fmaxf(m9, m10), m11);
            const float a4 = fmaxf(fmaxf(m12, m13), m14);
            TM = fmaxf(fmaxf(fmaxf(a0, a1), a2), fmaxf(fmaxf(a3, a4), m15));

            const float s_local = __fsqrt_rn(__fadd_rn(TM, 1e-8f));

            unsigned bid = 0xffffffffu; unsigned bpos = 0; float bt_ = 0.0f;
#define SEL1(j, reg, sh) if (m##j == TM) {                                    \
            const unsigned idj = ((reg) >> (sh)) & 0xffffu;                   \
            if (idj < bid) { bid = idj; bpos = (unsigned)(t * PPT + (j));     \
                             bt_ = pt##j; } }
            SEL1(0, id2_0, 0)  SEL1(1, id2_0, 16)
            SEL1(2, id2_1, 0)  SEL1(3, id2_1, 16)
            SEL1(4, id2_2, 0)  SEL1(5, id2_2, 16)
            SEL1(6, id2_3, 0)  SEL1(7, id2_3, 16)
            SEL1(8, id2_4, 0)  SEL1(9, id2_4, 16)
            SEL1(10, id2_5, 0) SEL1(11, id2_5, 16)
            SEL1(12, id2_6, 0) SEL1(13, id2_6, 16)
            SEL1(14, id2_7, 0) SEL1(15, id2_7, 16)
#undef SEL1

            // sqrt-collapse guard: >=2 slots within 32 ulps of TM?
            const unsigned tmu = __float_as_uint(TM);
            const float thresh = __uint_as_float(tmu >= 32u ? tmu - 32u : 0u);
            float cntw = 0.0f;
#define CNTV(i) cntw += (m##i >= thresh) ? 1.0f : 0.0f;
            R16(CNTV)
#undef CNTV
            if (cntw > 1.5f) {     // rare: verify window slots in s-domain
                bid = 0xffffffffu; bpos = 0; bt_ = 0.0f;
#define FIX1(j, reg, sh) if (m##j >= thresh) {                                \
                const float sj = __fsqrt_rn(__fadd_rn(m##j, 1e-8f));          \
                if (sj == s_local) {                                          \
                    const unsigned idj = ((reg) >> (sh)) & 0xffffu;           \
                    if (idj < bid) { bid = idj;                               \
                        bpos = (unsigned)(t * PPT + (j)); bt_ = pt##j; } } }
                FIX1(0, id2_0, 0)  FIX1(1, id2_0, 16)
                FIX1(2, id2_1, 0)  FIX1(3, id2_1, 16)
                FIX1(4, id2_2, 0)  FIX1(5, id2_2, 16)
                FIX1(6, id2_3, 0)  FIX1(7, id2_3, 16)
                FIX1(8, id2_4, 0)  FIX1(9, id2_4, 16)
                FIX1(10, id2_5, 0) FIX1(11, id2_5, 16)
                FIX1(12, id2_6, 0) FIX1(13, id2_6, 16)
                FIX1(14, id2_7, 0) FIX1(15, id2_7, 16)
#undef FIX1
            }
            // pack: max key = (max s, then min orig id); pos rides along
            skey = (((unsigned long long)__float_as_uint(s_local)) << 32) |
                   (((unsigned long long)(unsigned)(N_ - 1 - (int)bid)) << 14) |
                   (unsigned long long)bpos;
            sbt = bt_;
        }

        // ---- wave reduce (skipped when no lane updated: wave key cached)
        if (__any(upd)) {
            unsigned long long kk = skey; float tt2 = sbt;
#pragma unroll
            for (int off = 1; off < 64; off <<= 1) {
                const unsigned long long ok = __shfl_xor(kk, off);
                const float ot = __shfl_xor(tt2, off);
                if (ok > kk) { kk = ok; tt2 = ot; }
            }
            wkey = kk; wbt = tt2;
        }
        if (lane == 0) {
            ulonglong2 wv2;
            wv2.x = wkey;
            wv2.y = (unsigned long long)__float_as_uint(wbt);
            red[par][wave] = wv2;
        }
        __syncthreads();                            // the ONLY barrier

        // ---- all threads: scan 16 (key,t) structs (broadcast b128 reads)
        const ulonglong2* rp = &red[par][0];
        ulonglong2 best = rp[0];
#pragma unroll
        for (int w = 1; w < 16; ++w) {
            const ulonglong2 o = rp[w];
            if (o.x > best.x) best = o;
        }
        const unsigned pos = (unsigned)(best.x & 0x3fffu);
        const int gi = N_ - 1 - (int)((best.x >> 14) & 0x3fffu);
        lt = __uint_as_float((unsigned)best.y);
        const float2 wv = cxy[(pos & 15u) * TPB + (pos >> 4)];  // broadcast
        lx = wv.x; ly = wv.y;
        if (t == 0) idx_out[b * M_ + k] = gi;
    }
}

// ---------------------------------------------------------------------------
// Kernel 2: gather coords/times/polarities at sampled indices.
// ---------------------------------------------------------------------------
__global__ __launch_bounds__(256) void gather_kernel(
    const float* __restrict__ coords, const float* __restrict__ times,
    const float* __restrict__ pol, const int* __restrict__ idx,
    float* __restrict__ out)
{
    int i = blockIdx.x * 256 + threadIdx.x;       // 0 .. B_*M_-1
    if (i >= B_ * M_) return;
    int b = i >> 12;                              // / M_
    int g = b * N_ + idx[i];
    float2 c2 = *(const float2*)(coords + 2 * (size_t)g);
    *(float2*)(out + COFF + 2 * (size_t)i) = c2;
    out[TOFF + i] = times[g];
    out[POFF + i] = pol[g];
}

// ---------------------------------------------------------------------------
// Kernel 3: gathered GEMM + bias.  C[row, o] = features[src(row), :] . W[o, :]
// ---------------------------------------------------------------------------
#define BM 32
#define BN 128
#define BK 32

__global__ __launch_bounds__(256) void proj_kernel(
    const float* __restrict__ features, const float* __restrict__ W,
    const float* __restrict__ bias, const int* __restrict__ idx,
    float* __restrict__ out)
{
    __shared__ float a_lds[BK][BM + 4];
    __shared__ float w_lds[BK][BN];
    __shared__ int   src[BM];

    const int t = threadIdx.x;
    const int rowBase = blockIdx.x * BM;
    const int oBase = blockIdx.y * BN;

    if (t < BM) {
        int row = rowBase + t;
        int b = row >> 12;                // / M_
        src[t] = b * N_ + idx[row];
    }
    __syncthreads();

    const int rt = t >> 5;
    const int ot = t & 31;
    const int lr = t >> 3;
    const int lk = (t & 7) * 4;

    float c[4][4] = {};

    for (int kc = 0; kc < D_; kc += BK) {
        {
            float4 v = *(const float4*)(features + (size_t)src[lr] * D_ + kc + lk);
            a_lds[lk + 0][lr] = v.x; a_lds[lk + 1][lr] = v.y;
            a_lds[lk + 2][lr] = v.z; a_lds[lk + 3][lr] = v.w;
        }
#pragma unroll
        for (int p = 0; p < 4; ++p) {
            int o = p * 32 + lr;
            float4 v = *(const float4*)(W + (size_t)(oBase + o) * D_ + kc + lk);
            w_lds[lk + 0][o] = v.x; w_lds[lk + 1][o] = v.y;
            w_lds[lk + 2][o] = v.z; w_lds[lk + 3][o] = v.w;
        }
        __syncthreads();

#pragma unroll
        for (int k = 0; k < BK; ++k) {
            float4 af = *(const float4*)&a_lds[k][rt * 4];
            float4 wf = *(const float4*)&w_lds[k][ot * 4];
            float av[4] = { af.x, af.y, af.z, af.w };
            float wv[4] = { wf.x, wf.y, wf.z, wf.w };
#pragma unroll
            for (int ri = 0; ri < 4; ++ri)
#pragma unroll
                for (int oi = 0; oi < 4; ++oi)
                    c[ri][oi] = fmaf(av[ri], wv[oi], c[ri][oi]);
        }
        __syncthreads();
    }

    float4 bv = *(const float4*)(bias + oBase + ot * 4);
    float bvv[4] = { bv.x, bv.y, bv.z, bv.w };
#pragma unroll
    for (int ri = 0; ri < 4; ++ri) {
        int row = rowBase + rt * 4 + ri;
        float4 o4;
        o4.x = c[ri][0] + bvv[0];
        o4.y = c[ri][1] + bvv[1];
        o4.z = c[ri][2] + bvv[2];
        o4.w = c[ri][3] + bvv[3];
        *(float4*)(out + (size_t)row * D_ + oBase + ot * 4) = o4;
    }
}

// ---------------------------------------------------------------------------
// Kernel 4: LayerNorm in place over the proj output. One wave per row.
// ---------------------------------------------------------------------------
__global__ __launch_bounds__(256) void ln_kernel(
    float* __restrict__ out, const float* __restrict__ gamma,
    const float* __restrict__ beta)
{
    const int w = threadIdx.x >> 6;
    const int lane = threadIdx.x & 63;
    const size_t row = (size_t)blockIdx.x * 4 + w;
    float* p = out + row * D_;

    float4 v0 = *(const float4*)(p + lane * 8);
    float4 v1 = *(const float4*)(p + lane * 8 + 4);
    float x[8] = { v0.x, v0.y, v0.z, v0.w, v1.x, v1.y, v1.z, v1.w };

    float sum = 0.f;
#pragma unroll
    for (int i = 0; i < 8; ++i) sum += x[i];
#pragma unroll
    for (int off = 1; off < 64; off <<= 1) sum += __shfl_xor(sum, off);
    const float mu = sum * (1.0f / 512.0f);

    float sq = 0.f;
#pragma unroll
    for (int i = 0; i < 8; ++i) { float d = x[i] - mu; sq = fmaf(d, d, sq); }
#pragma unroll
    for (int off = 1; off < 64; off <<= 1) sq += __shfl_xor(sq, off);
    const float inv = rsqrtf(sq * (1.0f / 512.0f) + 1e-5f);

    float4 g0 = *(const float4*)(gamma + lane * 8);
    float4 g1 = *(const float4*)(gamma + lane * 8 + 4);
    float4 b0 = *(const float4*)(beta + lane * 8);
    float4 b1 = *(const float4*)(beta + lane * 8 + 4);
    float g[8] = { g0.x, g0.y, g0.z, g0.w, g1.x, g1.y, g1.z, g1.w };
    float be[8] = { b0.x, b0.y, b0.z, b0.w, b1.x, b1.y, b1.z, b1.w };

    float y[8];
#pragma unroll
    for (int i = 0; i < 8; ++i) y[i] = fmaf((x[i] - mu) * inv, g[i], be[i]);

    float4 o0 = { y[0], y[1], y[2], y[3] };
    float4 o1 = { y[4], y[5], y[6], y[7] };
    *(float4*)(p + lane * 8) = o0;
    *(float4*)(p + lane * 8 + 4) = o1;
}

// ---------------------------------------------------------------------------
extern "C" void kernel_launch(void* const* d_in, const int* in_sizes, int n_in,
                              void* d_out, int out_size, void* d_ws, size_t ws_size,
                              hipStream_t stream)
{
    const float* features   = (const float*)d_in[0];
    const float* coords     = (const float*)d_in[1];
    const float* times      = (const float*)d_in[2];
    const float* polarities = (const float*)d_in[3];
    const float* W          = (const float*)d_in[4];
    const float* bias       = (const float*)d_in[5];
    const float* gamma      = (const float*)d_in[6];
    const float* beta       = (const float*)d_in[7];
    float* out = (float*)d_out;

    // ws layout: [0, 128K) idx; then sortx/sorty/sortt/sortid (512K each)
    int* idx = (int*)d_ws;
    float* sortx = (float*)((char*)d_ws + (size_t)B_ * M_ * 4);
    float* sorty = sortx + (size_t)B_ * N_;
    float* sortt = sorty + (size_t)B_ * N_;
    unsigned* sortid = (unsigned*)(sortt + (size_t)B_ * N_);

    msort_kernel<<<B_, TPB, 0, stream>>>(coords, times, sortx, sorty, sortt, sortid);

    fps_kernel<<<B_, TPB, 0, stream>>>(coords, times, sortx, sorty, sortt,
                                       sortid, idx);

    gather_kernel<<<(B_ * M_ + 255) / 256, 256, 0, stream>>>(
        coords, times, polarities, idx, out);

    dim3 pgrid(B_ * M_ / BM, D_ / BN);            // (1024, 4)
    proj_kernel<<<pgrid, 256, 0, stream>>>(features, W, bias, idx, out);

    ln_kernel<<<B_ * M_ / 4, 256, 0, stream>>>(out, gamma, beta);
}

// Round 13
// 7490.243 us; speedup vs baseline: 1.3425x; 1.3425x over previous
//
#include <hip/hip_runtime.h>
#include <math.h>

#define B_ 8
#define N_ 16384
#define M_ 4096
#define D_ 512
#define TPB 1024
#define PPT 16          // N_ / TPB points per thread

#define FEAT_SZ (B_ * M_ * D_)          // 16777216
#define COFF FEAT_SZ                    // coords_out
#define TOFF (FEAT_SZ + 2 * B_ * M_)    // times_out
#define POFF (TOFF + B_ * M_)           // pol_out

#define R16(F) F(0) F(1) F(2) F(3) F(4) F(5) F(6) F(7) \
               F(8) F(9) F(10) F(11) F(12) F(13) F(14) F(15)

// DPP row ctrl: row_shr:n = 0x110|n, row_bcast15 = 0x142, row_bcast31 = 0x143.
template <int CTRL>
__device__ __forceinline__ float dpp_max_step(float x) {
    const int y = __builtin_amdgcn_update_dpp(0, __float_as_int(x),
                                              CTRL, 0xf, 0xf, true);
    return fmaxf(x, __int_as_float(y));   // invalid lanes read 0; s values > 0
}

__device__ __forceinline__ unsigned spread4(unsigned v) {
    return (v & 1u) | ((v & 2u) << 2) | ((v & 4u) << 4) | ((v & 8u) << 6);
}
__device__ __forceinline__ unsigned mcode(float x, float y, float tt) {
    unsigned mx = min((unsigned)(int)(x * 16.0f), 15u);
    unsigned my = min((unsigned)(int)(y * 16.0f), 15u);
    unsigned mt = min((unsigned)(int)(tt * 16.0f), 15u);
    return spread4(mx) | (spread4(my) << 1) | (spread4(mt) << 2);   // 12-bit Morton
}

// ---------------------------------------------------------------------------
// Kernel 0: Morton counting-sort (per batch) — unchanged (verified r11/r12).
// ---------------------------------------------------------------------------
__global__ __launch_bounds__(TPB) void msort_kernel(
    const float* __restrict__ coords, const float* __restrict__ times,
    float* __restrict__ sortx, float* __restrict__ sorty,
    float* __restrict__ sortt, unsigned* __restrict__ sortid)
{
    const int b = blockIdx.x, t = threadIdx.x;
    const float* cb = coords + (size_t)b * N_ * 2;
    const float* tb = times + (size_t)b * N_;
    const size_t bo = (size_t)b * N_;

    __shared__ unsigned cnt[4096];
    __shared__ unsigned wsum[TPB];

    for (int i = t; i < 4096; i += TPB) cnt[i] = 0;
    __syncthreads();

    for (int j = 0; j < PPT; ++j) {                 // count
        const int gi = j * TPB + t;
        const float2 c2 = *(const float2*)(cb + 2 * (size_t)gi);
        atomicAdd(&cnt[mcode(c2.x, c2.y, tb[gi])], 1u);
    }
    __syncthreads();

    {   // exclusive prefix sum over 4096
        const unsigned c0 = cnt[4 * t], c1 = cnt[4 * t + 1],
                       c2 = cnt[4 * t + 2], c3 = cnt[4 * t + 3];
        wsum[t] = c0 + c1 + c2 + c3;
        __syncthreads();
        if (t == 0) {
            unsigned run = 0;
            for (int i = 0; i < TPB; ++i) { unsigned v = wsum[i]; wsum[i] = run; run += v; }
        }
        __syncthreads();
        const unsigned base = wsum[t];
        cnt[4 * t] = base;
        cnt[4 * t + 1] = base + c0;
        cnt[4 * t + 2] = base + c0 + c1;
        cnt[4 * t + 3] = base + c0 + c1 + c2;
    }
    __syncthreads();

    for (int j = 0; j < PPT; ++j) {                 // scatter
        const int gi = j * TPB + t;
        const float2 c2 = *(const float2*)(cb + 2 * (size_t)gi);
        const float tt = tb[gi];
        const unsigned pos = atomicAdd(&cnt[mcode(c2.x, c2.y, tt)], 1u);
        sortx[bo + pos] = c2.x;
        sorty[bo + pos] = c2.y;
        sortt[bo + pos] = tt;
        sortid[bo + pos] = (unsigned)gi;
    }
}

// ---------------------------------------------------------------------------
// Kernel 1: FPS, exact bbox pruning, key-computed-in-update, lean tail.
//
// Bit-exact chain (verified r2-r12): d2 = fma(dz,dz, fma(dx,dx, dy*dy));
// s = sqrt_rn(fadd_rn(d2,1e-8)); min in d2 domain; s-domain argmax,
// first-ORIG-index tie-break, sqrt-collapse ulp-window fixup.
//
// r12 autopsy: u64 shfl_xor butterfly (~18 ds_bpermute, 6-deep chain) poisoned
// the reduce — cross-lane reduce must stay f32 DPP. Kept from r12: the packed
// winner key (origid<<46 | pos<<32 | t_bits) is computed in the PRUNED update
// path and cached while skipping, so the serial tail is only:
//   DPP f32 max -> red_s[wave] -> bar1 -> 16-float scan ->
//   (winner threads) ONE LDS atomicMin(cached key) -> bar2 ->
//   unpack origid/pos/t + one cxy[pos] broadcast read.
// atomicMin => min orig id = jnp.argmax first-occurrence; ids unique.
// ---------------------------------------------------------------------------
__global__ __launch_bounds__(TPB)
__attribute__((amdgpu_waves_per_eu(4, 4)))
void fps_kernel(
    const float* __restrict__ coords, const float* __restrict__ times,
    const float* __restrict__ sortx, const float* __restrict__ sorty,
    const float* __restrict__ sortt, const unsigned* __restrict__ sortid,
    int* __restrict__ idx_out)
{
    const int b = blockIdx.x;
    const int t = threadIdx.x;
    const float* cb = coords + (size_t)b * N_ * 2;
    const float* tb = times + (size_t)b * N_;
    const size_t bo = (size_t)b * N_;

    __shared__ float2 cxy[N_];          // sorted pos p at [(p&15)*TPB + (p>>4)]
    __shared__ __align__(16) float red_s[16];
    __shared__ unsigned long long nxt[2];           // winner key, parity dbuf

#define DECLV(i) float pt##i, m##i;
    R16(DECLV)
#undef DECLV
    unsigned id2_0, id2_1, id2_2, id2_3, id2_4, id2_5, id2_6, id2_7;

    float bx0 = 1e30f, bx1 = -1e30f, by0 = 1e30f, by1 = -1e30f,
          bt0 = 1e30f, bt1 = -1e30f;

#define LOADV(i) { const int p = t * PPT + (i);                               \
        const float x = sortx[bo + p], y = sorty[bo + p], tt = sortt[bo + p]; \
        float2 v2; v2.x = x; v2.y = y;                                        \
        cxy[(i) * TPB + t] = v2;                                              \
        pt##i = tt; m##i = INFINITY;                                          \
        bx0 = fminf(bx0, x); bx1 = fmaxf(bx1, x);                             \
        by0 = fminf(by0, y); by1 = fmaxf(by1, y);                             \
        bt0 = fminf(bt0, tt); bt1 = fmaxf(bt1, tt); }
    R16(LOADV)
#undef LOADV

#define LOADID(r) id2_##r = (sortid[bo + t * PPT + 2 * (r)] & 0xffffu) |      \
                            (sortid[bo + t * PPT + 2 * (r) + 1] << 16);
    LOADID(0) LOADID(1) LOADID(2) LOADID(3)
    LOADID(4) LOADID(5) LOADID(6) LOADID(7)
#undef LOADID

#define PINV(i) asm("" : "+v"(pt##i));
    R16(PINV)
#undef PINV
    asm("" : "+v"(id2_0), "+v"(id2_1), "+v"(id2_2), "+v"(id2_3));
    asm("" : "+v"(id2_4), "+v"(id2_5), "+v"(id2_6), "+v"(id2_7));

    if (t == 0) {
        idx_out[b * M_] = 0;                        // deterministic seed
        nxt[0] = ~0ull; nxt[1] = ~0ull;
    }
    float lx = cb[0], ly = cb[1], lt = tb[0];
    float TM = INFINITY;
    float s_local = 0.0f;                           // set at k=1 (forced update)
    unsigned long long skey = ~0ull;                // cached packed candidate
    __syncthreads();

    const int wave = t >> 6;
    const int lane = t & 63;

    for (int k = 1; k < M_; ++k) {
        const int par = k & 1;

        // ---- exact bbox skip test (k=1: TM=INF -> update forced)
        const float ddx = fmaxf(fmaxf(bx0 - lx, lx - bx1), 0.0f);
        const float ddy = fmaxf(fmaxf(by0 - ly, ly - by1), 0.0f);
        const float ddt = fmaxf(fmaxf(bt0 - lt, lt - bt1), 0.0f);
        const float lb2 = __fmaf_rn(ddt, ddt,
                          __fmaf_rn(ddx, ddx, __fmul_rn(ddy, ddy)));

        if (!(lb2 * 0.999996f >= TM)) {
            // ---- update path (pruned): refresh mins, TM, s_local, skey
#define UPDV(i) { const float2 c2 = cxy[(i) * TPB + t];                       \
            const float dx = c2.x - lx;                                       \
            const float dy = c2.y - ly;                                       \
            const float dz = pt##i - lt;                                      \
            const float d2 = __fmaf_rn(dz, dz, __fmaf_rn(dx, dx,              \
                                                     __fmul_rn(dy, dy)));     \
            m##i = fminf(m##i, d2); }
            R16(UPDV)
#undef UPDV
            const float a0 = fmaxf(fmaxf(m0, m1), m2);
            const float a1 = fmaxf(fmaxf(m3, m4), m5);
            const float a2 = fmaxf(fmaxf(m6, m7), m8);
            const float a3 = fmaxf(fmaxf(m9, m10), m11);
            const float a4 = fmaxf(fmaxf(m12, m13), m14);
            TM = fmaxf(fmaxf(fmaxf(a0, a1), a2), fmaxf(fmaxf(a3, a4), m15));

            s_local = __fsqrt_rn(__fadd_rn(TM, 1e-8f));

            unsigned bid = 0xffffffffu; unsigned bpos = 0; float bt_ = 0.0f;
#define SEL1(j, reg, sh) if (m##j == TM) {                                    \
            const unsigned idj = ((reg) >> (sh)) & 0xffffu;                   \
            if (idj < bid) { bid = idj; bpos = (unsigned)(t * PPT + (j));     \
                             bt_ = pt##j; } }
            SEL1(0, id2_0, 0)  SEL1(1, id2_0, 16)
            SEL1(2, id2_1, 0)  SEL1(3, id2_1, 16)
            SEL1(4, id2_2, 0)  SEL1(5, id2_2, 16)
            SEL1(6, id2_3, 0)  SEL1(7, id2_3, 16)
            SEL1(8, id2_4, 0)  SEL1(9, id2_4, 16)
            SEL1(10, id2_5, 0) SEL1(11, id2_5, 16)
            SEL1(12, id2_6, 0) SEL1(13, id2_6, 16)
            SEL1(14, id2_7, 0) SEL1(15, id2_7, 16)
#undef SEL1

            // sqrt-collapse guard: >=2 slots within 32 ulps of TM?
            const unsigned tmu = __float_as_uint(TM);
            const float thresh = __uint_as_float(tmu >= 32u ? tmu - 32u : 0u);
            float cntw = 0.0f;
#define CNTV(i) cntw += (m##i >= thresh) ? 1.0f : 0.0f;
            R16(CNTV)
#undef CNTV
            if (cntw > 1.5f) {     // rare: verify window slots in s-domain
                bid = 0xffffffffu; bpos = 0; bt_ = 0.0f;
#define FIX1(j, reg, sh) if (m##j >= thresh) {                                \
                const float sj = __fsqrt_rn(__fadd_rn(m##j, 1e-8f));          \
                if (sj == s_local) {                                          \
                    const unsigned idj = ((reg) >> (sh)) & 0xffffu;           \
                    if (idj < bid) { bid = idj;                               \
                        bpos = (unsigned)(t * PPT + (j)); bt_ = pt##j; } } }
                FIX1(0, id2_0, 0)  FIX1(1, id2_0, 16)
                FIX1(2, id2_1, 0)  FIX1(3, id2_1, 16)
                FIX1(4, id2_2, 0)  FIX1(5, id2_2, 16)
                FIX1(6, id2_3, 0)  FIX1(7, id2_3, 16)
                FIX1(8, id2_4, 0)  FIX1(9, id2_4, 16)
                FIX1(10, id2_5, 0) FIX1(11, id2_5, 16)
                FIX1(12, id2_6, 0) FIX1(13, id2_6, 16)
                FIX1(14, id2_7, 0) FIX1(15, id2_7, 16)
#undef FIX1
            }
            // packed key: min origid dominates; pos and t ride along
            skey = (((unsigned long long)bid) << 46) |
                   (((unsigned long long)bpos) << 32) |
                   (unsigned long long)__float_as_uint(bt_);
        }

        // ---- lean tail: f32 DPP wave max (VALU pipe, r12's u64 butterfly
        // is banned: ~800cy ds_bpermute chain)
        float v = s_local;
        v = dpp_max_step<0x111>(v);   // row_shr:1
        v = dpp_max_step<0x112>(v);   // row_shr:2
        v = dpp_max_step<0x114>(v);   // row_shr:4
        v = dpp_max_step<0x118>(v);   // row_shr:8
        v = dpp_max_step<0x142>(v);   // row_bcast:15
        v = dpp_max_step<0x143>(v);   // row_bcast:31
        if (lane == 63) red_s[wave] = v;
        __syncthreads();                              // bar1

        if (t == 0) nxt[par ^ 1] = ~0ull;             // reset other parity

        const float4* rp = (const float4*)red_s;
        const float4 r0 = rp[0], r1 = rp[1], r2 = rp[2], r3 = rp[3];
        const float s_star = fmaxf(
            fmaxf(fmaxf(fmaxf(r0.x, r0.y), fmaxf(r0.z, r0.w)),
                  fmaxf(fmaxf(r1.x, r1.y), fmaxf(r1.z, r1.w))),
            fmaxf(fmaxf(fmaxf(r2.x, r2.y), fmaxf(r2.z, r2.w)),
                  fmaxf(fmaxf(r3.x, r3.y), fmaxf(r3.z, r3.w))));

        // winner threads: publish the CACHED key — no SEL/CNT in the tail
        if (s_local == s_star) atomicMin(&nxt[par], skey);
        __syncthreads();                              // bar2

        const unsigned long long wk = nxt[par];
        const int gi = (int)(wk >> 46);
        const unsigned pos = (unsigned)(wk >> 32) & 0x3fffu;
        lt = __uint_as_float((unsigned)wk);
        const float2 wv = cxy[(pos & 15u) * TPB + (pos >> 4)];  // broadcast
        lx = wv.x; ly = wv.y;
        if (t == 0) idx_out[b * M_ + k] = gi;
    }
}

// ---------------------------------------------------------------------------
// Kernel 2: gather coords/times/polarities at sampled indices.
// ---------------------------------------------------------------------------
__global__ __launch_bounds__(256) void gather_kernel(
    const float* __restrict__ coords, const float* __restrict__ times,
    const float* __restrict__ pol, const int* __restrict__ idx,
    float* __restrict__ out)
{
    int i = blockIdx.x * 256 + threadIdx.x;       // 0 .. B_*M_-1
    if (i >= B_ * M_) return;
    int b = i >> 12;                              // / M_
    int g = b * N_ + idx[i];
    float2 c2 = *(const float2*)(coords + 2 * (size_t)g);
    *(float2*)(out + COFF + 2 * (size_t)i) = c2;
    out[TOFF + i] = times[g];
    out[POFF + i] = pol[g];
}

// ---------------------------------------------------------------------------
// Kernel 3: gathered GEMM + bias.  C[row, o] = features[src(row), :] . W[o, :]
// ---------------------------------------------------------------------------
#define BM 32
#define BN 128
#define BK 32

__global__ __launch_bounds__(256) void proj_kernel(
    const float* __restrict__ features, const float* __restrict__ W,
    const float* __restrict__ bias, const int* __restrict__ idx,
    float* __restrict__ out)
{
    __shared__ float a_lds[BK][BM + 4];
    __shared__ float w_lds[BK][BN];
    __shared__ int   src[BM];

    const int t = threadIdx.x;
    const int rowBase = blockIdx.x * BM;
    const int oBase = blockIdx.y * BN;

    if (t < BM) {
        int row = rowBase + t;
        int b = row >> 12;                // / M_
        src[t] = b * N_ + idx[row];
    }
    __syncthreads();

    const int rt = t >> 5;
    const int ot = t & 31;
    const int lr = t >> 3;
    const int lk = (t & 7) * 4;

    float c[4][4] = {};

    for (int kc = 0; kc < D_; kc += BK) {
        {
            float4 v = *(const float4*)(features + (size_t)src[lr] * D_ + kc + lk);
            a_lds[lk + 0][lr] = v.x; a_lds[lk + 1][lr] = v.y;
            a_lds[lk + 2][lr] = v.z; a_lds[lk + 3][lr] = v.w;
        }
#pragma unroll
        for (int p = 0; p < 4; ++p) {
            int o = p * 32 + lr;
            float4 v = *(const float4*)(W + (size_t)(oBase + o) * D_ + kc + lk);
            w_lds[lk + 0][o] = v.x; w_lds[lk + 1][o] = v.y;
            w_lds[lk + 2][o] = v.z; w_lds[lk + 3][o] = v.w;
        }
        __syncthreads();

#pragma unroll
        for (int k = 0; k < BK; ++k) {
            float4 af = *(const float4*)&a_lds[k][rt * 4];
            float4 wf = *(const float4*)&w_lds[k][ot * 4];
            float av[4] = { af.x, af.y, af.z, af.w };
            float wv[4] = { wf.x, wf.y, wf.z, wf.w };
#pragma unroll
            for (int ri = 0; ri < 4; ++ri)
#pragma unroll
                for (int oi = 0; oi < 4; ++oi)
                    c[ri][oi] = fmaf(av[ri], wv[oi], c[ri][oi]);
        }
        __syncthreads();
    }

    float4 bv = *(const float4*)(bias + oBase + ot * 4);
    float bvv[4] = { bv.x, bv.y, bv.z, bv.w };
#pragma unroll
    for (int ri = 0; ri < 4; ++ri) {
        int row = rowBase + rt * 4 + ri;
        float4 o4;
        o4.x = c[ri][0] + bvv[0];
        o4.y = c[ri][1] + bvv[1];
        o4.z = c[ri][2] + bvv[2];
        o4.w = c[ri][3] + bvv[3];
        *(float4*)(out + (size_t)row * D_ + oBase + ot * 4) = o4;
    }
}

// ---------------------------------------------------------------------------
// Kernel 4: LayerNorm in place over the proj output. One wave per row.
// ---------------------------------------------------------------------------
__global__ __launch_bounds__(256) void ln_kernel(
    float* __restrict__ out, const float* __restrict__ gamma,
    const float* __restrict__ beta)
{
    const int w = threadIdx.x >> 6;
    const int lane = threadIdx.x & 63;
    const size_t row = (size_t)blockIdx.x * 4 + w;
    float* p = out + row * D_;

    float4 v0 = *(const float4*)(p + lane * 8);
    float4 v1 = *(const float4*)(p + lane * 8 + 4);
    float x[8] = { v0.x, v0.y, v0.z, v0.w, v1.x, v1.y, v1.z, v1.w };

    float sum = 0.f;
#pragma unroll
    for (int i = 0; i < 8; ++i) sum += x[i];
#pragma unroll
    for (int off = 1; off < 64; off <<= 1) sum += __shfl_xor(sum, off);
    const float mu = sum * (1.0f / 512.0f);

    float sq = 0.f;
#pragma unroll
    for (int i = 0; i < 8; ++i) { float d = x[i] - mu; sq = fmaf(d, d, sq); }
#pragma unroll
    for (int off = 1; off < 64; off <<= 1) sq += __shfl_xor(sq, off);
    const float inv = rsqrtf(sq * (1.0f / 512.0f) + 1e-5f);

    float4 g0 = *(const float4*)(gamma + lane * 8);
    float4 g1 = *(const float4*)(gamma + lane * 8 + 4);
    float4 b0 = *(const float4*)(beta + lane * 8);
    float4 b1 = *(const float4*)(beta + lane * 8 + 4);
    float g[8] = { g0.x, g0.y, g0.z, g0.w, g1.x, g1.y, g1.z, g1.w };
    float be[8] = { b0.x, b0.y, b0.z, b0.w, b1.x, b1.y, b1.z, b1.w };

    float y[8];
#pragma unroll
    for (int i = 0; i < 8; ++i) y[i] = fmaf((x[i] - mu) * inv, g[i], be[i]);

    float4 o0 = { y[0], y[1], y[2], y[3] };
    float4 o1 = { y[4], y[5], y[6], y[7] };
    *(float4*)(p + lane * 8) = o0;
    *(float4*)(p + lane * 8 + 4) = o1;
}

// ---------------------------------------------------------------------------
extern "C" void kernel_launch(void* const* d_in, const int* in_sizes, int n_in,
                              void* d_out, int out_size, void* d_ws, size_t ws_size,
                              hipStream_t stream)
{
    const float* features   = (const float*)d_in[0];
    const float* coords     = (const float*)d_in[1];
    const float* times      = (const float*)d_in[2];
    const float* polarities = (const float*)d_in[3];
    const float* W          = (const float*)d_in[4];
    const float* bias       = (const float*)d_in[5];
    const float* gamma      = (const float*)d_in[6];
    const float* beta       = (const float*)d_in[7];
    float* out = (float*)d_out;

    // ws layout: [0, 128K) idx; then sortx/sorty/sortt/sortid (512K each)
    int* idx = (int*)d_ws;
    float* sortx = (float*)((char*)d_ws + (size_t)B_ * M_ * 4);
    float* sorty = sortx + (size_t)B_ * N_;
    float* sortt = sorty + (size_t)B_ * N_;
    unsigned* sortid = (unsigned*)(sortt + (size_t)B_ * N_);

    msort_kernel<<<B_, TPB, 0, stream>>>(coords, times, sortx, sorty, sortt, sortid);

    fps_kernel<<<B_, TPB, 0, stream>>>(coords, times, sortx, sorty, sortt,
                                       sortid, idx);

    gather_kernel<<<(B_ * M_ + 255) / 256, 256, 0, stream>>>(
        coords, times, polarities, idx, out);

    dim3 pgrid(B_ * M_ / BM, D_ / BN);            // (1024, 4)
    proj_kernel<<<pgrid, 256, 0, stream>>>(features, W, bias, idx, out);

    ln_kernel<<<B_ * M_ / 4, 256, 0, stream>>>(out, gamma, beta);
}

// Round 14
// 6214.326 us; speedup vs baseline: 1.6182x; 1.2053x over previous
//
#include <hip/hip_runtime.h>
#include <math.h>

#define B_ 8
#define N_ 16384
#define M_ 4096
#define D_ 512
#define TPB 1024
#define PPT 16          // N_ / TPB points per thread

#define FEAT_SZ (B_ * M_ * D_)          // 16777216
#define COFF FEAT_SZ                    // coords_out
#define TOFF (FEAT_SZ + 2 * B_ * M_)    // times_out
#define POFF (TOFF + B_ * M_)           // pol_out

#define R16(F) F(0) F(1) F(2) F(3) F(4) F(5) F(6) F(7) \
               F(8) F(9) F(10) F(11) F(12) F(13) F(14) F(15)
// descending order: select chains end at the SMALLEST index (first occurrence)
#define R16D(F) F(15) F(14) F(13) F(12) F(11) F(10) F(9) F(8) \
                F(7) F(6) F(5) F(4) F(3) F(2) F(1) F(0)

// DPP row ctrl codes: row_shr:n = 0x110|n, row_bcast15 = 0x142, row_bcast31 = 0x143.
template <int CTRL>
__device__ __forceinline__ float dpp_max_step(float x) {
    const int y = __builtin_amdgcn_update_dpp(0, __float_as_int(x),
                                              CTRL, 0xf, 0xf, true);
    return fmaxf(x, __int_as_float(y));   // invalid lanes read 0; s values > 0
}

// ---------------------------------------------------------------------------
// Kernel 1: farthest point sampling, one block per batch.  [r10 revert]
//
// This is the measured-best structure (round 10: fps 5.89 ms, 6.21 ms total).
// Rounds 11-13 (Morton sort + exact bbox pruning, cached keys, lean tails)
// all regressed: pruning cuts VALU 2x but converts the kernel from
// issue-bound (89% per-active-CU VALUBusy, 4-wave latency hiding) to
// latency-bound on a lone Morton-local update wave + barrier skeleton.
// Work redistribution is blocked by LDS capacity (x,y,t,m = 256KB > 160KB).
//
// Bit-exact chain (verified r2-r10): d2 = fma(dz,dz, fma(dx,dx, dy*dy));
// s = sqrt_rn(fadd_rn(d2,1e-8)). Min in d2 domain (commutes with monotone
// sqrt chain). Value phase: bm = max_i m_i (8 VALU/pt, no index tracking);
// s_local = s(bm); DPP wave max; bar1; all threads scan 16 wave maxima.
// Index phase (winner threads only, execz-skipped elsewhere):
//   common: min slot with m_i == bm exactly (descending select, carries pt_i);
//   rare (>=2 slots within 32-ulp window of bm): sqrt-verify window slots
//           (sqrt-collapse ties), min flat index with s == s_local.
//   publish: ONE LDS atomicMin of (flat<<32 | t_bits) -> min flat index wins
//   (jnp.argmax first-occurrence), its t rides as payload.
// bar2; all threads: gi/lt from the key, lx/ly from cxy[gi] (LDS read).
// ---------------------------------------------------------------------------
__global__ __launch_bounds__(TPB)
__attribute__((amdgpu_waves_per_eu(4, 4)))
void fps_kernel(
    const float* __restrict__ coords, const float* __restrict__ times,
    int* __restrict__ idx_out)
{
    const int b = blockIdx.x;
    const int t = threadIdx.x;
    const float* cb = coords + (size_t)b * N_ * 2;
    const float* tb = times + (size_t)b * N_;

    __shared__ float2 cxy[N_];                        // 128 KiB point coords
    __shared__ __align__(16) float red_s[16];         // per-wave value maxima
    __shared__ unsigned long long nxt[2];             // winner key, parity dbuf

#define DECLV(i) float pt##i, m##i;
    R16(DECLV)
#undef DECLV

#define LOADV(i) { const int gi = (i) * TPB + t;                              \
        const float2 c2 = *(const float2*)(cb + 2 * (size_t)gi);              \
        cxy[gi] = c2; pt##i = tb[gi]; m##i = INFINITY; }
    R16(LOADV)
#undef LOADV

#define PINV(i) asm("" : "+v"(pt##i));
    R16(PINV)
#undef PINV

    if (t == 0) {
        idx_out[b * M_] = 0;                          // deterministic seed
        nxt[0] = ~0ull; nxt[1] = ~0ull;
    }
    float lx = cb[0], ly = cb[1], lt = tb[0];
    __syncthreads();

    const int wave = t >> 6;
    const int lane = t & 63;

    for (int k = 1; k < M_; ++k) {
        const int par = k & 1;
        float bm = -INFINITY;

        // ---- value phase: d2-min update + running max (no index tracking)
#define UPDV(i) {                                                             \
        const float2 c2 = cxy[(i) * TPB + t];                                 \
        const float dx = c2.x - lx;                                           \
        const float dy = c2.y - ly;                                           \
        const float dz = pt##i - lt;                                          \
        const float d2 = __fmaf_rn(dz, dz, __fmaf_rn(dx, dx,                  \
                                                     __fmul_rn(dy, dy)));     \
        m##i = fminf(m##i, d2);                                               \
        bm = fmaxf(bm, m##i); }
        R16(UPDV)
#undef UPDV

        const float s_local = __fsqrt_rn(__fadd_rn(bm, 1e-8f));

        // DPP wave-max (VALU pipe): lane 63 ends with the wave max
        float v = s_local;
        v = dpp_max_step<0x111>(v);   // row_shr:1
        v = dpp_max_step<0x112>(v);   // row_shr:2
        v = dpp_max_step<0x114>(v);   // row_shr:4
        v = dpp_max_step<0x118>(v);   // row_shr:8
        v = dpp_max_step<0x142>(v);   // row_bcast:15
        v = dpp_max_step<0x143>(v);   // row_bcast:31
        if (lane == 63) red_s[wave] = v;
        __syncthreads();                              // bar1

        if (t == 0) nxt[par ^ 1] = ~0ull;             // reset other parity

        // all threads: block max from 16 floats (vector reads + max tree)
        const float4* rp = (const float4*)red_s;
        const float4 r0 = rp[0], r1 = rp[1], r2 = rp[2], r3 = rp[3];
        const float s_star = fmaxf(
            fmaxf(fmaxf(fmaxf(r0.x, r0.y), fmaxf(r0.z, r0.w)),
                  fmaxf(fmaxf(r1.x, r1.y), fmaxf(r1.z, r1.w))),
            fmaxf(fmaxf(fmaxf(r2.x, r2.y), fmaxf(r2.z, r2.w)),
                  fmaxf(fmaxf(r3.x, r3.y), fmaxf(r3.z, r3.w))));

        // ---- index phase: winners only (execz-skipped in non-winner waves)
        if (s_local == s_star) {
            // common case: min flat index with m_i == bm exactly, t rides
            int   fj = 0x7fffffff;
            float ft = 0.f;
#define SELV(i) if (m##i == bm) { fj = (i) * TPB + t; ft = pt##i; }
            R16D(SELV)
#undef SELV

            // sqrt-collapse guard: >=2 slots within 32 ulps of bm?
            const unsigned bmu = __float_as_uint(bm);
            const float thresh = __uint_as_float(bmu >= 32u ? bmu - 32u : 0u);
            float cnt = 0.f;
#define CNTV(i) cnt += (m##i >= thresh) ? 1.0f : 0.0f;
            R16(CNTV)
#undef CNTV
            if (cnt > 1.5f) {   // rare: verify window slots in s domain
#define FIXV(i) if (m##i >= thresh) {                                         \
                const float si = __fsqrt_rn(__fadd_rn(m##i, 1e-8f));          \
                if (si == s_local) { fj = (i) * TPB + t; ft = pt##i; } }
                R16D(FIXV)
#undef FIXV
            }
            atomicMin(&nxt[par],
                      (((unsigned long long)(unsigned)fj) << 32) |
                      __float_as_uint(ft));
        }
        __syncthreads();                              // bar2

        const unsigned long long wk = nxt[par];
        const int gi = (int)(wk >> 32);
        lt = __uint_as_float((unsigned)wk);
        const float2 wv = cxy[gi];                    // LDS broadcast read
        lx = wv.x; ly = wv.y;
        if (t == 0) idx_out[b * M_ + k] = gi;
    }
}

// ---------------------------------------------------------------------------
// Kernel 2: gather coords/times/polarities at sampled indices.
// ---------------------------------------------------------------------------
__global__ __launch_bounds__(256) void gather_kernel(
    const float* __restrict__ coords, const float* __restrict__ times,
    const float* __restrict__ pol, const int* __restrict__ idx,
    float* __restrict__ out)
{
    int i = blockIdx.x * 256 + threadIdx.x;       // 0 .. B_*M_-1
    if (i >= B_ * M_) return;
    int b = i >> 12;                              // / M_
    int g = b * N_ + idx[i];
    float2 c2 = *(const float2*)(coords + 2 * (size_t)g);
    *(float2*)(out + COFF + 2 * (size_t)i) = c2;
    out[TOFF + i] = times[g];
    out[POFF + i] = pol[g];
}

// ---------------------------------------------------------------------------
// Kernel 3: gathered GEMM + bias.  C[row, o] = features[src(row), :] . W[o, :]
// ---------------------------------------------------------------------------
#define BM 32
#define BN 128
#define BK 32

__global__ __launch_bounds__(256) void proj_kernel(
    const float* __restrict__ features, const float* __restrict__ W,
    const float* __restrict__ bias, const int* __restrict__ idx,
    float* __restrict__ out)
{
    __shared__ float a_lds[BK][BM + 4];
    __shared__ float w_lds[BK][BN];
    __shared__ int   src[BM];

    const int t = threadIdx.x;
    const int rowBase = blockIdx.x * BM;
    const int oBase = blockIdx.y * BN;

    if (t < BM) {
        int row = rowBase + t;
        int b = row >> 12;                // / M_
        src[t] = b * N_ + idx[row];
    }
    __syncthreads();

    const int rt = t >> 5;        // 0..7   -> rows rt*4..rt*4+3
    const int ot = t & 31;        // 0..31  -> outs ot*4..ot*4+3
    const int lr = t >> 3;        // 0..31  staging row / out
    const int lk = (t & 7) * 4;   // 0,4,...,28 staging k

    float c[4][4] = {};

    for (int kc = 0; kc < D_; kc += BK) {
        {
            float4 v = *(const float4*)(features + (size_t)src[lr] * D_ + kc + lk);
            a_lds[lk + 0][lr] = v.x; a_lds[lk + 1][lr] = v.y;
            a_lds[lk + 2][lr] = v.z; a_lds[lk + 3][lr] = v.w;
        }
#pragma unroll
        for (int p = 0; p < 4; ++p) {
            int o = p * 32 + lr;
            float4 v = *(const float4*)(W + (size_t)(oBase + o) * D_ + kc + lk);
            w_lds[lk + 0][o] = v.x; w_lds[lk + 1][o] = v.y;
            w_lds[lk + 2][o] = v.z; w_lds[lk + 3][o] = v.w;
        }
        __syncthreads();

#pragma unroll
        for (int k = 0; k < BK; ++k) {
            float4 af = *(const float4*)&a_lds[k][rt * 4];
            float4 wf = *(const float4*)&w_lds[k][ot * 4];
            float av[4] = { af.x, af.y, af.z, af.w };
            float wv[4] = { wf.x, wf.y, wf.z, wf.w };
#pragma unroll
            for (int ri = 0; ri < 4; ++ri)
#pragma unroll
                for (int oi = 0; oi < 4; ++oi)
                    c[ri][oi] = fmaf(av[ri], wv[oi], c[ri][oi]);
        }
        __syncthreads();
    }

    float4 bv = *(const float4*)(bias + oBase + ot * 4);
    float bvv[4] = { bv.x, bv.y, bv.z, bv.w };
#pragma unroll
    for (int ri = 0; ri < 4; ++ri) {
        int row = rowBase + rt * 4 + ri;
        float4 o4;
        o4.x = c[ri][0] + bvv[0];
        o4.y = c[ri][1] + bvv[1];
        o4.z = c[ri][2] + bvv[2];
        o4.w = c[ri][3] + bvv[3];
        *(float4*)(out + (size_t)row * D_ + oBase + ot * 4) = o4;
    }
}

// ---------------------------------------------------------------------------
// Kernel 4: LayerNorm in place over the proj output. One wave per row.
// ---------------------------------------------------------------------------
__global__ __launch_bounds__(256) void ln_kernel(
    float* __restrict__ out, const float* __restrict__ gamma,
    const float* __restrict__ beta)
{
    const int w = threadIdx.x >> 6;
    const int lane = threadIdx.x & 63;
    const size_t row = (size_t)blockIdx.x * 4 + w;
    float* p = out + row * D_;

    float4 v0 = *(const float4*)(p + lane * 8);
    float4 v1 = *(const float4*)(p + lane * 8 + 4);
    float x[8] = { v0.x, v0.y, v0.z, v0.w, v1.x, v1.y, v1.z, v1.w };

    float sum = 0.f;
#pragma unroll
    for (int i = 0; i < 8; ++i) sum += x[i];
#pragma unroll
    for (int off = 1; off < 64; off <<= 1) sum += __shfl_xor(sum, off);
    const float mu = sum * (1.0f / 512.0f);

    float sq = 0.f;
#pragma unroll
    for (int i = 0; i < 8; ++i) { float d = x[i] - mu; sq = fmaf(d, d, sq); }
#pragma unroll
    for (int off = 1; off < 64; off <<= 1) sq += __shfl_xor(sq, off);
    const float inv = rsqrtf(sq * (1.0f / 512.0f) + 1e-5f);

    float4 g0 = *(const float4*)(gamma + lane * 8);
    float4 g1 = *(const float4*)(gamma + lane * 8 + 4);
    float4 b0 = *(const float4*)(beta + lane * 8);
    float4 b1 = *(const float4*)(beta + lane * 8 + 4);
    float g[8] = { g0.x, g0.y, g0.z, g0.w, g1.x, g1.y, g1.z, g1.w };
    float be[8] = { b0.x, b0.y, b0.z, b0.w, b1.x, b1.y, b1.z, b1.w };

    float y[8];
#pragma unroll
    for (int i = 0; i < 8; ++i) y[i] = fmaf((x[i] - mu) * inv, g[i], be[i]);

    float4 o0 = { y[0], y[1], y[2], y[3] };
    float4 o1 = { y[4], y[5], y[6], y[7] };
    *(float4*)(p + lane * 8) = o0;
    *(float4*)(p + lane * 8 + 4) = o1;
}

// ---------------------------------------------------------------------------
extern "C" void kernel_launch(void* const* d_in, const int* in_sizes, int n_in,
                              void* d_out, int out_size, void* d_ws, size_t ws_size,
                              hipStream_t stream)
{
    const float* features   = (const float*)d_in[0];
    const float* coords     = (const float*)d_in[1];
    const float* times      = (const float*)d_in[2];
    const float* polarities = (const float*)d_in[3];
    const float* W          = (const float*)d_in[4];
    const float* bias       = (const float*)d_in[5];
    const float* gamma      = (const float*)d_in[6];
    const float* beta       = (const float*)d_in[7];
    float* out = (float*)d_out;

    int* idx = (int*)d_ws;                        // B_*M_ ints = 128 KiB scratch

    fps_kernel<<<B_, TPB, 0, stream>>>(coords, times, idx);

    gather_kernel<<<(B_ * M_ + 255) / 256, 256, 0, stream>>>(
        coords, times, polarities, idx, out);

    dim3 pgrid(B_ * M_ / BM, D_ / BN);            // (1024, 4)
    proj_kernel<<<pgrid, 256, 0, stream>>>(features, W, bias, idx, out);

    ln_kernel<<<B_ * M_ / 4, 256, 0, stream>>>(out, gamma, beta);
}

// Round 15
// 5755.981 us; speedup vs baseline: 1.7470x; 1.0796x over previous
//
#include <hip/hip_runtime.h>
#include <math.h>

#define B_ 8
#define N_ 16384
#define M_ 4096
#define D_ 512
#define TPB 1024
#define PPT 16          // N_ / TPB points per thread

#define FEAT_SZ (B_ * M_ * D_)          // 16777216
#define COFF FEAT_SZ                    // coords_out
#define TOFF (FEAT_SZ + 2 * B_ * M_)    // times_out
#define POFF (TOFF + B_ * M_)           // pol_out

#define R16(F) F(0) F(1) F(2) F(3) F(4) F(5) F(6) F(7) \
               F(8) F(9) F(10) F(11) F(12) F(13) F(14) F(15)
// descending order: select chains end at the SMALLEST index (first occurrence)
#define R16D(F) F(15) F(14) F(13) F(12) F(11) F(10) F(9) F(8) \
                F(7) F(6) F(5) F(4) F(3) F(2) F(1) F(0)

// DPP row ctrl codes: row_shr:n = 0x110|n, row_bcast15 = 0x142, row_bcast31 = 0x143.
template <int CTRL>
__device__ __forceinline__ float dpp_max_step(float x) {
    const int y = __builtin_amdgcn_update_dpp(0, __float_as_int(x),
                                              CTRL, 0xf, 0xf, true);
    return fmaxf(x, __int_as_float(y));   // invalid lanes read 0; s values > 0
}

// ---------------------------------------------------------------------------
// Kernel 1: farthest point sampling, one block per batch.
//
// r15 change vs the r10/r14 baseline: the per-thread point coords (px,py)
// are VOLATILE-pinned into VGPRs. r7's non-volatile asm("" : "+v") pins were
// legally rematerializable (side-effect-free asm can be duplicated), which is
// why the allocator kept re-loading coords; volatile asm executes exactly
// once, making its output an unrepeatable def — the values must stay register
// resident (scratch spill won't happen: ~90 live < 128 budget at
// waves_per_eu(4,4)). This removes all 16 ds_read_b64/thread/iter from the
// value phase (~1500 cy/CU/iter of LDS-pipe issue in the r10 structure);
// LDS keeps one cxy copy solely for the winner broadcast lookup.
//
// Bit-exact chain (verified r2-r14): d2 = fma(dz,dz, fma(dx,dx, dy*dy));
// s = sqrt_rn(fadd_rn(d2,1e-8)). Min in d2 domain (commutes with monotone
// sqrt chain). Value phase: bm = max_i m_i (8 VALU/pt, no index tracking);
// s_local = s(bm); DPP wave max; bar1; all threads scan 16 wave maxima.
// Index phase (winner threads only, execz-skipped elsewhere):
//   common: min slot with m_i == bm exactly (descending select, carries pt_i);
//   rare (>=2 slots within 32-ulp window of bm): sqrt-verify window slots
//           (sqrt-collapse ties), min flat index with s == s_local.
//   publish: ONE LDS atomicMin of (flat<<32 | t_bits) -> min flat index wins
//   (jnp.argmax first-occurrence), its t rides as payload.
// bar2; all threads: gi/lt from the key, lx/ly from cxy[gi] (LDS read).
// ---------------------------------------------------------------------------
__global__ __launch_bounds__(TPB)
__attribute__((amdgpu_waves_per_eu(4, 4)))
void fps_kernel(
    const float* __restrict__ coords, const float* __restrict__ times,
    int* __restrict__ idx_out)
{
    const int b = blockIdx.x;
    const int t = threadIdx.x;
    const float* cb = coords + (size_t)b * N_ * 2;
    const float* tb = times + (size_t)b * N_;

    __shared__ float2 cxy[N_];                        // winner-lookup copy
    __shared__ __align__(16) float red_s[16];         // per-wave value maxima
    __shared__ unsigned long long nxt[2];             // winner key, parity dbuf

#define DECLV(i) float px##i, py##i, pt##i, m##i;
    R16(DECLV)
#undef DECLV

#define LOADV(i) { const int gi = (i) * TPB + t;                              \
        const float2 c2 = *(const float2*)(cb + 2 * (size_t)gi);              \
        cxy[gi] = c2; px##i = c2.x; py##i = c2.y; pt##i = tb[gi];             \
        m##i = INFINITY; }
    R16(LOADV)
#undef LOADV

    // VOLATILE pins: unrepeatable defs -> values must stay in VGPRs
    // (non-volatile asm pins are rematerializable — the r7 failure mode).
#define PINV(i) asm volatile("" : "+v"(px##i), "+v"(py##i), "+v"(pt##i));
    R16(PINV)
#undef PINV

    if (t == 0) {
        idx_out[b * M_] = 0;                          // deterministic seed
        nxt[0] = ~0ull; nxt[1] = ~0ull;
    }
    float lx = cb[0], ly = cb[1], lt = tb[0];
    __syncthreads();

    const int wave = t >> 6;
    const int lane = t & 63;

    for (int k = 1; k < M_; ++k) {
        const int par = k & 1;
        float bm = -INFINITY;

        // ---- value phase: pure-register d2-min update + running max
#define UPDV(i) {                                                             \
        const float dx = px##i - lx;                                          \
        const float dy = py##i - ly;                                          \
        const float dz = pt##i - lt;                                          \
        const float d2 = __fmaf_rn(dz, dz, __fmaf_rn(dx, dx,                  \
                                                     __fmul_rn(dy, dy)));     \
        m##i = fminf(m##i, d2);                                               \
        bm = fmaxf(bm, m##i); }
        R16(UPDV)
#undef UPDV

        const float s_local = __fsqrt_rn(__fadd_rn(bm, 1e-8f));

        // DPP wave-max (VALU pipe): lane 63 ends with the wave max
        float v = s_local;
        v = dpp_max_step<0x111>(v);   // row_shr:1
        v = dpp_max_step<0x112>(v);   // row_shr:2
        v = dpp_max_step<0x114>(v);   // row_shr:4
        v = dpp_max_step<0x118>(v);   // row_shr:8
        v = dpp_max_step<0x142>(v);   // row_bcast:15
        v = dpp_max_step<0x143>(v);   // row_bcast:31
        if (lane == 63) red_s[wave] = v;
        __syncthreads();                              // bar1

        if (t == 0) nxt[par ^ 1] = ~0ull;             // reset other parity

        // all threads: block max from 16 floats (vector reads + max tree)
        const float4* rp = (const float4*)red_s;
        const float4 r0 = rp[0], r1 = rp[1], r2 = rp[2], r3 = rp[3];
        const float s_star = fmaxf(
            fmaxf(fmaxf(fmaxf(r0.x, r0.y), fmaxf(r0.z, r0.w)),
                  fmaxf(fmaxf(r1.x, r1.y), fmaxf(r1.z, r1.w))),
            fmaxf(fmaxf(fmaxf(r2.x, r2.y), fmaxf(r2.z, r2.w)),
                  fmaxf(fmaxf(r3.x, r3.y), fmaxf(r3.z, r3.w))));

        // ---- index phase: winners only (execz-skipped in non-winner waves)
        if (s_local == s_star) {
            // common case: min flat index with m_i == bm exactly, t rides
            int   fj = 0x7fffffff;
            float ft = 0.f;
#define SELV(i) if (m##i == bm) { fj = (i) * TPB + t; ft = pt##i; }
            R16D(SELV)
#undef SELV

            // sqrt-collapse guard: >=2 slots within 32 ulps of bm?
            const unsigned bmu = __float_as_uint(bm);
            const float thresh = __uint_as_float(bmu >= 32u ? bmu - 32u : 0u);
            float cnt = 0.f;
#define CNTV(i) cnt += (m##i >= thresh) ? 1.0f : 0.0f;
            R16(CNTV)
#undef CNTV
            if (cnt > 1.5f) {   // rare: verify window slots in s domain
#define FIXV(i) if (m##i >= thresh) {                                         \
                const float si = __fsqrt_rn(__fadd_rn(m##i, 1e-8f));          \
                if (si == s_local) { fj = (i) * TPB + t; ft = pt##i; } }
                R16D(FIXV)
#undef FIXV
            }
            atomicMin(&nxt[par],
                      (((unsigned long long)(unsigned)fj) << 32) |
                      __float_as_uint(ft));
        }
        __syncthreads();                              // bar2

        const unsigned long long wk = nxt[par];
        const int gi = (int)(wk >> 32);
        lt = __uint_as_float((unsigned)wk);
        const float2 wv = cxy[gi];                    // LDS broadcast read
        lx = wv.x; ly = wv.y;
        if (t == 0) idx_out[b * M_ + k] = gi;
    }
}

// ---------------------------------------------------------------------------
// Kernel 2: gather coords/times/polarities at sampled indices.
// ---------------------------------------------------------------------------
__global__ __launch_bounds__(256) void gather_kernel(
    const float* __restrict__ coords, const float* __restrict__ times,
    const float* __restrict__ pol, const int* __restrict__ idx,
    float* __restrict__ out)
{
    int i = blockIdx.x * 256 + threadIdx.x;       // 0 .. B_*M_-1
    if (i >= B_ * M_) return;
    int b = i >> 12;                              // / M_
    int g = b * N_ + idx[i];
    float2 c2 = *(const float2*)(coords + 2 * (size_t)g);
    *(float2*)(out + COFF + 2 * (size_t)i) = c2;
    out[TOFF + i] = times[g];
    out[POFF + i] = pol[g];
}

// ---------------------------------------------------------------------------
// Kernel 3: gathered GEMM + bias.  C[row, o] = features[src(row), :] . W[o, :]
// ---------------------------------------------------------------------------
#define BM 32
#define BN 128
#define BK 32

__global__ __launch_bounds__(256) void proj_kernel(
    const float* __restrict__ features, const float* __restrict__ W,
    const float* __restrict__ bias, const int* __restrict__ idx,
    float* __restrict__ out)
{
    __shared__ float a_lds[BK][BM + 4];
    __shared__ float w_lds[BK][BN];
    __shared__ int   src[BM];

    const int t = threadIdx.x;
    const int rowBase = blockIdx.x * BM;
    const int oBase = blockIdx.y * BN;

    if (t < BM) {
        int row = rowBase + t;
        int b = row >> 12;                // / M_
        src[t] = b * N_ + idx[row];
    }
    __syncthreads();

    const int rt = t >> 5;        // 0..7   -> rows rt*4..rt*4+3
    const int ot = t & 31;        // 0..31  -> outs ot*4..ot*4+3
    const int lr = t >> 3;        // 0..31  staging row / out
    const int lk = (t & 7) * 4;   // 0,4,...,28 staging k

    float c[4][4] = {};

    for (int kc = 0; kc < D_; kc += BK) {
        {
            float4 v = *(const float4*)(features + (size_t)src[lr] * D_ + kc + lk);
            a_lds[lk + 0][lr] = v.x; a_lds[lk + 1][lr] = v.y;
            a_lds[lk + 2][lr] = v.z; a_lds[lk + 3][lr] = v.w;
        }
#pragma unroll
        for (int p = 0; p < 4; ++p) {
            int o = p * 32 + lr;
            float4 v = *(const float4*)(W + (size_t)(oBase + o) * D_ + kc + lk);
            w_lds[lk + 0][o] = v.x; w_lds[lk + 1][o] = v.y;
            w_lds[lk + 2][o] = v.z; w_lds[lk + 3][o] = v.w;
        }
        __syncthreads();

#pragma unroll
        for (int k = 0; k < BK; ++k) {
            float4 af = *(const float4*)&a_lds[k][rt * 4];
            float4 wf = *(const float4*)&w_lds[k][ot * 4];
            float av[4] = { af.x, af.y, af.z, af.w };
            float wv[4] = { wf.x, wf.y, wf.z, wf.w };
#pragma unroll
            for (int ri = 0; ri < 4; ++ri)
#pragma unroll
                for (int oi = 0; oi < 4; ++oi)
                    c[ri][oi] = fmaf(av[ri], wv[oi], c[ri][oi]);
        }
        __syncthreads();
    }

    float4 bv = *(const float4*)(bias + oBase + ot * 4);
    float bvv[4] = { bv.x, bv.y, bv.z, bv.w };
#pragma unroll
    for (int ri = 0; ri < 4; ++ri) {
        int row = rowBase + rt * 4 + ri;
        float4 o4;
        o4.x = c[ri][0] + bvv[0];
        o4.y = c[ri][1] + bvv[1];
        o4.z = c[ri][2] + bvv[2];
        o4.w = c[ri][3] + bvv[3];
        *(float4*)(out + (size_t)row * D_ + oBase + ot * 4) = o4;
    }
}

// ---------------------------------------------------------------------------
// Kernel 4: LayerNorm in place over the proj output. One wave per row.
// ---------------------------------------------------------------------------
__global__ __launch_bounds__(256) void ln_kernel(
    float* __restrict__ out, const float* __restrict__ gamma,
    const float* __restrict__ beta)
{
    const int w = threadIdx.x >> 6;
    const int lane = threadIdx.x & 63;
    const size_t row = (size_t)blockIdx.x * 4 + w;
    float* p = out + row * D_;

    float4 v0 = *(const float4*)(p + lane * 8);
    float4 v1 = *(const float4*)(p + lane * 8 + 4);
    float x[8] = { v0.x, v0.y, v0.z, v0.w, v1.x, v1.y, v1.z, v1.w };

    float sum = 0.f;
#pragma unroll
    for (int i = 0; i < 8; ++i) sum += x[i];
#pragma unroll
    for (int off = 1; off < 64; off <<= 1) sum += __shfl_xor(sum, off);
    const float mu = sum * (1.0f / 512.0f);

    float sq = 0.f;
#pragma unroll
    for (int i = 0; i < 8; ++i) { float d = x[i] - mu; sq = fmaf(d, d, sq); }
#pragma unroll
    for (int off = 1; off < 64; off <<= 1) sq += __shfl_xor(sq, off);
    const float inv = rsqrtf(sq * (1.0f / 512.0f) + 1e-5f);

    float4 g0 = *(const float4*)(gamma + lane * 8);
    float4 g1 = *(const float4*)(gamma + lane * 8 + 4);
    float4 b0 = *(const float4*)(beta + lane * 8);
    float4 b1 = *(const float4*)(beta + lane * 8 + 4);
    float g[8] = { g0.x, g0.y, g0.z, g0.w, g1.x, g1.y, g1.z, g1.w };
    float be[8] = { b0.x, b0.y, b0.z, b0.w, b1.x, b1.y, b1.z, b1.w };

    float y[8];
#pragma unroll
    for (int i = 0; i < 8; ++i) y[i] = fmaf((x[i] - mu) * inv, g[i], be[i]);

    float4 o0 = { y[0], y[1], y[2], y[3] };
    float4 o1 = { y[4], y[5], y[6], y[7] };
    *(float4*)(p + lane * 8) = o0;
    *(float4*)(p + lane * 8 + 4) = o1;
}

// ---------------------------------------------------------------------------
extern "C" void kernel_launch(void* const* d_in, const int* in_sizes, int n_in,
                              void* d_out, int out_size, void* d_ws, size_t ws_size,
                              hipStream_t stream)
{
    const float* features   = (const float*)d_in[0];
    const float* coords     = (const float*)d_in[1];
    const float* times      = (const float*)d_in[2];
    const float* polarities = (const float*)d_in[3];
    const float* W          = (const float*)d_in[4];
    const float* bias       = (const float*)d_in[5];
    const float* gamma      = (const float*)d_in[6];
    const float* beta       = (const float*)d_in[7];
    float* out = (float*)d_out;

    int* idx = (int*)d_ws;                        // B_*M_ ints = 128 KiB scratch

    fps_kernel<<<B_, TPB, 0, stream>>>(coords, times, idx);

    gather_kernel<<<(B_ * M_ + 255) / 256, 256, 0, stream>>>(
        coords, times, polarities, idx, out);

    dim3 pgrid(B_ * M_ / BM, D_ / BN);            // (1024, 4)
    proj_kernel<<<pgrid, 256, 0, stream>>>(features, W, bias, idx, out);

    ln_kernel<<<B_ * M_ / 4, 256, 0, stream>>>(out, gamma, beta);
}